// Round 2
// baseline (2954.692 us; speedup 1.0000x reference)
//
#include <hip/hip_runtime.h>
#include <hip/hip_bf16.h>

// Problem constants (reference: B=2, C=256, H=100, W=152, K=1024 rois,
// OUT=7, SR=2, N_CLASSES*N_ANCHORS=42)
#define BB   2
#define CC   256
#define HH   100
#define WW   152
#define OUTS 7
#define CO5  42

// ---------------------------------------------------------------------------
// Kernel 1: NCHW -> NHWC feature transpose (tiled via LDS, conflict-free)
// ---------------------------------------------------------------------------
__global__ void ftrans_kernel(const float* __restrict__ f, float* __restrict__ ft) {
    __shared__ float tile[32][33];
    const int x0 = blockIdx.x * 32;
    const int c0 = blockIdx.y * 32;
    const int by = blockIdx.z;            // b*H + y
    const int b = by / HH, y = by % HH;
    const int tx = threadIdx.x, ty = threadIdx.y;
    #pragma unroll
    for (int j = 0; j < 4; ++j) {
        int c = c0 + ty + j * 8;
        int x = x0 + tx;
        if (x < WW)
            tile[ty + j * 8][tx] = f[(((size_t)b * CC + c) * HH + y) * WW + x];
    }
    __syncthreads();
    #pragma unroll
    for (int j = 0; j < 4; ++j) {
        int x = x0 + ty + j * 8;
        int c = c0 + tx;
        if (x < WW)
            ft[(((size_t)b * HH + y) * WW + x) * CC + c] = tile[tx][ty + j * 8];
    }
}

// ---------------------------------------------------------------------------
// Kernel 2: weight transpose [co][ci][3][3] -> [(ci*9+k)][co]  (coalesced out)
// ---------------------------------------------------------------------------
__global__ void wtrans_kernel(const float* __restrict__ W, float* __restrict__ Wt, int CO) {
    int idx = blockIdx.x * 256 + threadIdx.x;
    int total = CO * CC * 9;
    if (idx >= total) return;
    int co = idx % CO;
    int r  = idx / CO;        // r = ci*9 + k
    int ci = r / 9;
    int k  = r % 9;
    Wt[idx] = W[((size_t)co * CC + ci) * 9 + k];
}

// ---------------------------------------------------------------------------
// Kernel 3: RoI align.  block = roi, thread = channel.  ft is NHWC so the 4
// bilinear corners are coalesced 1KB wave reads.  Output layout [roi][px][ci].
// The reference `valid` mask is provably always-true for its clipped rois.
// ---------------------------------------------------------------------------
__global__ __launch_bounds__(256) void roialign_kernel(const float* __restrict__ ft,
                                                       const float* __restrict__ rois,
                                                       float* __restrict__ outb) {
    const int roi = blockIdx.x, t = threadIdx.x;
    const float bf = rois[roi * 5 + 0];
    const float x1 = rois[roi * 5 + 1];
    const float y1 = rois[roi * 5 + 2];
    const float x2 = rois[roi * 5 + 3];
    const float y2 = rois[roi * 5 + 4];
    const int b = (int)bf;
    const float rw = fmaxf(x2 - x1, 1.0f);
    const float rh = fmaxf(y2 - y1, 1.0f);
    const float stepy = rh / 7.0f;
    const float stepx = rw / 7.0f;
    const float* base = ft + (size_t)b * HH * WW * CC + t;

    for (int py = 0; py < OUTS; ++py) {
        for (int px = 0; px < OUTS; ++px) {
            float s = 0.0f;
            #pragma unroll
            for (int j = 0; j < 4; ++j) {
                const int syi = py * 2 + (j >> 1);
                const int sxi = px * 2 + (j & 1);
                // offs = (i+0.5)/SR ; g = lo + offs*(r/OUT)
                float gy = y1 + ((float)syi + 0.5f) * 0.5f * stepy;
                float gx = x1 + ((float)sxi + 0.5f) * 0.5f * stepx;
                float yc = fminf(fmaxf(gy, 0.0f), (float)(HH - 1));
                float xc = fminf(fmaxf(gx, 0.0f), (float)(WW - 1));
                float y0f = fminf(floorf(yc), (float)(HH - 2));
                float x0f = fminf(floorf(xc), (float)(WW - 2));
                float wy = yc - y0f;
                float wx = xc - x0f;
                int y0 = (int)y0f, x0 = (int)x0f;
                const float* p = base + ((size_t)y0 * WW + x0) * CC;
                float v00 = p[0];
                float v01 = p[CC];
                float v10 = p[(size_t)WW * CC];
                float v11 = p[(size_t)WW * CC + CC];
                s += (1.0f - wy) * ((1.0f - wx) * v00 + wx * v01)
                   +          wy * ((1.0f - wx) * v10 + wx * v11);
            }
            outb[((size_t)roi * 49 + py * 7 + px) * CC + t] = 0.25f * s;
        }
    }
}

// ---------------------------------------------------------------------------
// Kernel 4: 3x3 conv, 256->256 on 7x7, pad 1.  block = roi (256 thr, thread=co).
// Input staged in LDS [ci][7][8] (rows 16B aligned; compute reads are uniform
// broadcasts -> conflict-free).  Weights pre-transposed [(ci*9+k)][co] ->
// coalesced 256B wave loads, L2-resident (2.36 MB/layer).
// IN-PLACE SAFE: full roi tile staged behind __syncthreads before any write,
// and blocks never touch another roi's data -> in==out allowed.
// ---------------------------------------------------------------------------
__global__ __launch_bounds__(256, 2) void conv256_kernel(const float* __restrict__ in,
                                                         float* __restrict__ out,
                                                         const float* __restrict__ Wt,
                                                         const float* __restrict__ bias,
                                                         int relu) {
    __shared__ float s_in[CC * 56];   // [ci][7][8] = 57,344 B
    const int roi = blockIdx.x, t = threadIdx.x;

    const float* src = in + (size_t)roi * 49 * CC;
    #pragma unroll
    for (int px = 0; px < 49; ++px) {
        float v = src[(size_t)px * CC + t];
        s_in[t * 56 + (px / 7) * 8 + (px % 7)] = v;
    }
    __syncthreads();

    float acc[49];
    #pragma unroll
    for (int i = 0; i < 49; ++i) acc[i] = 0.0f;

    const float* wp = Wt + t;   // co = t
    for (int ci = 0; ci < CC; ++ci) {
        float w[9];
        #pragma unroll
        for (int k = 0; k < 9; ++k) w[k] = wp[((size_t)ci * 9 + k) * CC];
        const float* row = s_in + ci * 56;
        #pragma unroll
        for (int iy = 0; iy < 7; ++iy) {
            float4 Av = *(const float4*)(row + iy * 8);
            float4 Bv = *(const float4*)(row + iy * 8 + 4);
            float r[9];
            r[0] = 0.0f; r[1] = Av.x; r[2] = Av.y; r[3] = Av.z; r[4] = Av.w;
            r[5] = Bv.x; r[6] = Bv.y; r[7] = Bv.z; r[8] = 0.0f;
            #pragma unroll
            for (int ky = 0; ky < 3; ++ky) {
                const int y = iy + 1 - ky;
                if (0 <= y && y < 7) {
                    #pragma unroll
                    for (int kx = 0; kx < 3; ++kx) {
                        #pragma unroll
                        for (int x = 0; x < 7; ++x)
                            acc[y * 7 + x] += r[x + kx] * w[ky * 3 + kx];
                    }
                }
            }
        }
    }

    const float b = bias[t];
    #pragma unroll
    for (int px = 0; px < 49; ++px) {
        float v = acc[px] + b;
        if (relu) v = fmaxf(v, 0.0f);
        out[((size_t)roi * 49 + px) * CC + t] = v;   // coalesced (lane = co)
    }
}

// ---------------------------------------------------------------------------
// Kernel 5: final 3x3 conv 256->42.  4 wave-quarters each reduce 64 ci, then
// LDS tree-reduce (reusing the staging buffer) and coalesced output write.
// ---------------------------------------------------------------------------
__global__ __launch_bounds__(256, 2) void conv5_kernel(const float* __restrict__ in,
                                                       float* __restrict__ out,
                                                       const float* __restrict__ Wt5,
                                                       const float* __restrict__ b5) {
    __shared__ float s_in[CC * 56];
    const int roi = blockIdx.x, t = threadIdx.x;
    const int q = t >> 6;          // ci quarter
    const int col = t & 63;        // out-channel slot (42 active)

    const float* src = in + (size_t)roi * 49 * CC;
    #pragma unroll
    for (int px = 0; px < 49; ++px) {
        float v = src[(size_t)px * CC + t];
        s_in[t * 56 + (px / 7) * 8 + (px % 7)] = v;
    }
    __syncthreads();

    float acc[49];
    #pragma unroll
    for (int i = 0; i < 49; ++i) acc[i] = 0.0f;

    if (col < CO5) {
        const float* wp = Wt5 + col;
        const int ci0 = q * 64;
        for (int cil = 0; cil < 64; ++cil) {
            const int ci = ci0 + cil;
            float w[9];
            #pragma unroll
            for (int k = 0; k < 9; ++k) w[k] = wp[((size_t)ci * 9 + k) * CO5];
            const float* row = s_in + ci * 56;
            #pragma unroll
            for (int iy = 0; iy < 7; ++iy) {
                float4 Av = *(const float4*)(row + iy * 8);
                float4 Bv = *(const float4*)(row + iy * 8 + 4);
                float r[9];
                r[0] = 0.0f; r[1] = Av.x; r[2] = Av.y; r[3] = Av.z; r[4] = Av.w;
                r[5] = Bv.x; r[6] = Bv.y; r[7] = Bv.z; r[8] = 0.0f;
                #pragma unroll
                for (int ky = 0; ky < 3; ++ky) {
                    const int y = iy + 1 - ky;
                    if (0 <= y && y < 7) {
                        #pragma unroll
                        for (int kx = 0; kx < 3; ++kx) {
                            #pragma unroll
                            for (int x = 0; x < 7; ++x)
                                acc[y * 7 + x] += r[x + kx] * w[ky * 3 + kx];
                        }
                    }
                }
            }
        }
    }
    __syncthreads();   // all compute done; reuse s_in for partials
    if (col < CO5) {
        #pragma unroll
        for (int px = 0; px < 49; ++px)
            s_in[(q * 64 + col) * 49 + px] = acc[px];
    }
    __syncthreads();
    // reduce 4 partials, add bias, write (K,42,7,7) coalesced
    for (int i = t; i < CO5 * 49; i += 256) {
        int co = i / 49;
        float s = s_in[(0 * 64 + co) * 49 + (i % 49)]
                + s_in[(1 * 64 + co) * 49 + (i % 49)]
                + s_in[(2 * 64 + co) * 49 + (i % 49)]
                + s_in[(3 * 64 + co) * 49 + (i % 49)];
        out[(size_t)roi * (CO5 * 49) + i] = s + b5[co];
    }
}

// ---------------------------------------------------------------------------
extern "C" void kernel_launch(void* const* d_in, const int* in_sizes, int n_in,
                              void* d_out, int out_size, void* d_ws, size_t ws_size,
                              hipStream_t stream) {
    const float* features = (const float*)d_in[0];
    const float* rois     = (const float*)d_in[1];
    const float* W1 = (const float*)d_in[2];
    const float* b1 = (const float*)d_in[3];
    const float* W2 = (const float*)d_in[4];
    const float* b2 = (const float*)d_in[5];
    const float* W3 = (const float*)d_in[6];
    const float* b3 = (const float*)d_in[7];
    const float* W4 = (const float*)d_in[8];
    const float* b4 = (const float*)d_in[9];
    const float* W5 = (const float*)d_in[10];
    const float* b5 = (const float*)d_in[11];
    float* out = (float*)d_out;

    const int K = in_sizes[1] / 5;   // 1024 rois

    // workspace layout (floats) — single activation buffer (convs are in-place
    // safe; each block fully stages its roi tile into LDS before writing).
    float* ws = (float*)d_ws;
    const size_t ft_sz   = (size_t)BB * HH * WW * CC;   // 7,782,400
    const size_t wt_sz   = (size_t)CC * 9 * CC;         //   589,824
    const size_t wt5_sz  = (size_t)CC * 9 * CO5;        //    96,768
    const size_t buf_sz  = (size_t)K * 49 * CC;         // 12,845,056
    float* ft   = ws;
    float* Wt1  = ft  + ft_sz;
    float* Wt2  = Wt1 + wt_sz;
    float* Wt3  = Wt2 + wt_sz;
    float* Wt4  = Wt3 + wt_sz;
    float* Wt5  = Wt4 + wt_sz;
    float* buf0 = Wt5 + wt5_sz;
    // total: ~23.1M floats = 92.5 MB  (fits typical ws; halved from round 0)

    // 1. feature transpose NCHW -> NHWC
    {
        dim3 grid((WW + 31) / 32, CC / 32, BB * HH);
        dim3 block(32, 8);
        ftrans_kernel<<<grid, block, 0, stream>>>(features, ft);
    }
    // 2. weight transposes
    {
        int total = CC * 9 * CC;
        int nb = (total + 255) / 256;
        wtrans_kernel<<<nb, 256, 0, stream>>>(W1, Wt1, CC);
        wtrans_kernel<<<nb, 256, 0, stream>>>(W2, Wt2, CC);
        wtrans_kernel<<<nb, 256, 0, stream>>>(W3, Wt3, CC);
        wtrans_kernel<<<nb, 256, 0, stream>>>(W4, Wt4, CC);
        int total5 = CO5 * CC * 9;
        wtrans_kernel<<<(total5 + 255) / 256, 256, 0, stream>>>(W5, Wt5, CO5);
    }
    // 3. roi align -> buf0
    roialign_kernel<<<K, 256, 0, stream>>>(ft, rois, buf0);
    // 4. conv chain, in-place on buf0
    conv256_kernel<<<K, 256, 0, stream>>>(buf0, buf0, Wt1, b1, 1);
    conv256_kernel<<<K, 256, 0, stream>>>(buf0, buf0, Wt2, b2, 1);
    conv256_kernel<<<K, 256, 0, stream>>>(buf0, buf0, Wt3, b3, 1);
    conv256_kernel<<<K, 256, 0, stream>>>(buf0, buf0, Wt4, b4, 1);
    // 5. final conv -> d_out
    conv5_kernel<<<K, 256, 0, stream>>>(buf0, out, Wt5, b5);
}

// Round 4
// 1348.790 us; speedup vs baseline: 2.1906x; 2.1906x over previous
//
#include <hip/hip_runtime.h>
#include <hip/hip_bf16.h>

// Problem constants: B=2, C=256, H=100, W=152, K=1024 rois, OUT=7, co5=42
#define BB   2
#define CC   256
#define HH   100
#define WW   152
#define CO5  42

typedef short short8 __attribute__((ext_vector_type(8)));   // 8 bf16 (4 VGPRs)
typedef float f32x4 __attribute__((ext_vector_type(4)));    // MFMA accumulator

typedef unsigned int uint_t;
typedef unsigned short ushort_t;

__device__ __forceinline__ uint_t bf16_rne(float x) {
    uint_t u = __float_as_uint(x);
    return (u + 0x7fffu + ((u >> 16) & 1u)) >> 16;
}
__device__ __forceinline__ void split_bf16(float x, uint_t& h, uint_t& l) {
    h = bf16_rne(x);
    float hf = __uint_as_float(h << 16);
    l = bf16_rne(x - hf);     // x - hf exact in fp32
}

// ---------------------------------------------------------------------------
// Kernel 1: NCHW -> NHWC feature transpose (for coalesced roi-align gathers)
// ---------------------------------------------------------------------------
__global__ void ftrans_kernel(const float* __restrict__ f, float* __restrict__ ft) {
    __shared__ float tile[32][33];
    const int x0 = blockIdx.x * 32;
    const int c0 = blockIdx.y * 32;
    const int by = blockIdx.z;            // b*H + y
    const int b = by / HH, y = by % HH;
    const int tx = threadIdx.x, ty = threadIdx.y;
    #pragma unroll
    for (int j = 0; j < 4; ++j) {
        int c = c0 + ty + j * 8;
        int x = x0 + tx;
        if (x < WW)
            tile[ty + j * 8][tx] = f[(((size_t)b * CC + c) * HH + y) * WW + x];
    }
    __syncthreads();
    #pragma unroll
    for (int j = 0; j < 4; ++j) {
        int x = x0 + ty + j * 8;
        int c = c0 + tx;
        if (x < WW)
            ft[(((size_t)b * HH + y) * WW + x) * CC + c] = tile[tx][ty + j * 8];
    }
}

// ---------------------------------------------------------------------------
// Kernel 2: weight prep for 256->256 layers.
// W[co][ci][3][3] fp32  ->  wh/wl[tap][co][ci] bf16 (hi/lo split).
// ---------------------------------------------------------------------------
__global__ void wprep_kernel(const float* __restrict__ W,
                             ushort_t* __restrict__ wh, ushort_t* __restrict__ wl) {
    int idx = blockIdx.x * 256 + threadIdx.x;     // 9*256*256 = 589,824 exact
    int tap = idx >> 16;
    int rem = idx & 0xffff;
    int co = rem >> 8, ci = rem & 255;
    float v = W[(size_t)((co << 8) + ci) * 9 + tap];
    uint_t h, l; split_bf16(v, h, l);
    wh[idx] = (ushort_t)h;
    wl[idx] = (ushort_t)l;
}

// Weight prep for final layer: pad co 42 -> 48.  wh/wl[tap][48][256].
__global__ void wprep5_kernel(const float* __restrict__ W,
                              ushort_t* __restrict__ wh, ushort_t* __restrict__ wl) {
    int idx = blockIdx.x * 256 + threadIdx.x;     // 9*48*256 = 110,592 exact
    int tap = idx / 12288;
    int rem = idx % 12288;
    int co = rem >> 8, ci = rem & 255;
    float v = (co < CO5) ? W[(size_t)((co << 8) + ci) * 9 + tap] : 0.0f;
    uint_t h, l; split_bf16(v, h, l);
    wh[idx] = (ushort_t)h;
    wl[idx] = (ushort_t)l;
}

// ---------------------------------------------------------------------------
// Kernel 3: RoI align.  block = roi, thread = channel, NHWC gathers coalesced.
// Output [roi][px49][ci] fp32.  (valid-mask provably always true here.)
// ---------------------------------------------------------------------------
__global__ __launch_bounds__(256) void roialign_kernel(const float* __restrict__ ft,
                                                       const float* __restrict__ rois,
                                                       float* __restrict__ outb) {
    const int roi = blockIdx.x, t = threadIdx.x;
    const float bf = rois[roi * 5 + 0];
    const float x1 = rois[roi * 5 + 1];
    const float y1 = rois[roi * 5 + 2];
    const float x2 = rois[roi * 5 + 3];
    const float y2 = rois[roi * 5 + 4];
    const int b = (int)bf;
    const float rw = fmaxf(x2 - x1, 1.0f);
    const float rh = fmaxf(y2 - y1, 1.0f);
    const float stepy = rh / 7.0f;
    const float stepx = rw / 7.0f;
    const float* base = ft + (size_t)b * HH * WW * CC + t;

    for (int py = 0; py < 7; ++py) {
        for (int px = 0; px < 7; ++px) {
            float s = 0.0f;
            #pragma unroll
            for (int j = 0; j < 4; ++j) {
                const int syi = py * 2 + (j >> 1);
                const int sxi = px * 2 + (j & 1);
                float gy = y1 + ((float)syi + 0.5f) * 0.5f * stepy;
                float gx = x1 + ((float)sxi + 0.5f) * 0.5f * stepx;
                float yc = fminf(fmaxf(gy, 0.0f), (float)(HH - 1));
                float xc = fminf(fmaxf(gx, 0.0f), (float)(WW - 1));
                float y0f = fminf(floorf(yc), (float)(HH - 2));
                float x0f = fminf(floorf(xc), (float)(WW - 2));
                float wy = yc - y0f;
                float wx = xc - x0f;
                int y0 = (int)y0f, x0 = (int)x0f;
                const float* p = base + ((size_t)y0 * WW + x0) * CC;
                float v00 = p[0];
                float v01 = p[CC];
                float v10 = p[(size_t)WW * CC];
                float v11 = p[(size_t)WW * CC + CC];
                s += (1.0f - wy) * ((1.0f - wx) * v00 + wx * v01)
                   +          wy * ((1.0f - wx) * v10 + wx * v11);
            }
            outb[((size_t)roi * 49 + py * 7 + px) * CC + t] = 0.25f * s;
        }
    }
}

// ---------------------------------------------------------------------------
// Shared staging: fp32 roi tile [49][256] -> LDS hi/lo bf16 [64][256], rows
// 49..63 zeroed (row 63 = conv zero-pad row).  XOR swizzle on the FULL
// within-row byte offset: addr = row*512 + (byteoff ^ ((row&7)<<4)).
// ---------------------------------------------------------------------------
__device__ __forceinline__ void stage_roi(const float* __restrict__ src,
                                          ushort_t* Xh, ushort_t* Xl, int t) {
    const float2* s2 = (const float2*)src;
    const int half = t >> 7;          // 0/1: even/odd rows
    const int cw = t & 127;           // ci pair index
    #pragma unroll
    for (int i = 0; i < 25; ++i) {
        int row = i * 2 + half;
        if (row < 49) {
            float2 v = s2[row * 128 + cw];
            uint_t h0, l0, h1, l1;
            split_bf16(v.x, h0, l0);
            split_bf16(v.y, h1, l1);
            int addr = row * 512 + ((cw * 4) ^ ((row & 7) << 4));
            *(uint_t*)((char*)Xh + addr) = h0 | (h1 << 16);
            *(uint_t*)((char*)Xl + addr) = l0 | (l1 << 16);
        }
    }
    #pragma unroll
    for (int j = 0; j < 8; ++j) {
        int row = 49 + j * 2 + half;
        if (row < 64) {
            int addr = row * 512 + ((cw * 4) ^ ((row & 7) << 4));
            *(uint_t*)((char*)Xh + addr) = 0u;
            *(uint_t*)((char*)Xl + addr) = 0u;
        }
    }
}

// ---------------------------------------------------------------------------
// Kernel 4: 256->256 conv as 9 per-tap GEMMs on MFMA (split-bf16, 3 products).
// Block = roi (4 waves); wave w owns cols [64w,64w+64).  A rows remapped per
// tap via LDS row index (row 63 == zeros).  Weights from global [tap][co][ci]
// (L2-resident).  In-place safe.
// FIX (r3): read swizzle applies to the FULL within-row offset
//   (lk*16 + kc*64) ^ ((srow&7)<<4)  — same involution as the write side.
//   Previous code XOR'd only lk*16 then added kc*64 (bit-6 carry => OOB LDS
//   read at srow=63,kc=7 => NaN).
// ---------------------------------------------------------------------------
__global__ __launch_bounds__(256, 2) void conv_mfma_kernel(
        const float* __restrict__ in, float* __restrict__ out,
        const ushort_t* __restrict__ wh, const ushort_t* __restrict__ wl,
        const float* __restrict__ bias, int relu) {
    __shared__ ushort_t X[2][64 * 256];   // [hi/lo][row][ci]  = 64 KB
    const int roi = blockIdx.x, t = threadIdx.x;
    stage_roi(in + (size_t)roi * 49 * CC, X[0], X[1], t);
    __syncthreads();

    const int wv = t >> 6, l = t & 63;
    const int lr = l & 15;               // A-row-in-tile / B-col / D-col
    const int lk = l >> 4;               // k-group
    const int n0 = wv * 64;

    f32x4 acc[4][4];
    #pragma unroll
    for (int a = 0; a < 4; ++a)
        #pragma unroll
        for (int b = 0; b < 4; ++b) acc[a][b] = {0.f, 0.f, 0.f, 0.f};

    const int bvoff = ((n0 + lr) * 256 + lk * 8) * 2;   // byte off within tap
    const char* Xhc = (const char*)X[0];
    const char* Xlc = (const char*)X[1];
    const int lk16 = lk * 16;

    for (int tap = 0; tap < 9; ++tap) {
        const int ky = tap / 3 - 1, kx = tap % 3 - 1;
        int arow[4], amask[4];
        #pragma unroll
        for (int mt = 0; mt < 4; ++mt) {
            int m = mt * 16 + lr;
            int py = m / 7, px = m - py * 7;
            int y = py + ky, x = px + kx;
            bool ok = (m < 49) && (y >= 0) && (y < 7) && (x >= 0) && (x < 7);
            int srow = ok ? (y * 7 + x) : 63;          // 63 = zero row
            arow[mt]  = srow * 512;
            amask[mt] = (srow & 7) << 4;
        }
        const char* wht = (const char*)wh + tap * 131072;
        const char* wlt = (const char*)wl + tap * 131072;
        #pragma unroll
        for (int kc = 0; kc < 8; ++kc) {
            short8 ah[4], al[4];
            #pragma unroll
            for (int mt = 0; mt < 4; ++mt) {
                const int off = arow[mt] + ((lk16 + kc * 64) ^ amask[mt]);
                ah[mt] = *(const short8*)(Xhc + off);
                al[mt] = *(const short8*)(Xlc + off);
            }
            #pragma unroll
            for (int nt = 0; nt < 4; ++nt) {
                const int woff = bvoff + nt * 8192 + kc * 64;
                short8 bh = *(const short8*)(wht + woff);
                short8 bl = *(const short8*)(wlt + woff);
                #pragma unroll
                for (int mt = 0; mt < 4; ++mt)
                    acc[mt][nt] = __builtin_amdgcn_mfma_f32_16x16x32_bf16(ah[mt], bh, acc[mt][nt], 0, 0, 0);
                #pragma unroll
                for (int mt = 0; mt < 4; ++mt)
                    acc[mt][nt] = __builtin_amdgcn_mfma_f32_16x16x32_bf16(al[mt], bh, acc[mt][nt], 0, 0, 0);
                #pragma unroll
                for (int mt = 0; mt < 4; ++mt)
                    acc[mt][nt] = __builtin_amdgcn_mfma_f32_16x16x32_bf16(ah[mt], bl, acc[mt][nt], 0, 0, 0);
            }
        }
    }

    float* outp = out + (size_t)roi * 49 * CC;
    #pragma unroll
    for (int nt = 0; nt < 4; ++nt) {
        const int co = n0 + nt * 16 + lr;
        const float bv = bias[co];
        #pragma unroll
        for (int mt = 0; mt < 4; ++mt) {
            #pragma unroll
            for (int r = 0; r < 4; ++r) {
                int m = mt * 16 + lk * 4 + r;         // D row = (l>>4)*4+reg
                if (m < 49) {
                    float v = acc[mt][nt][r] + bv;
                    if (relu) v = fmaxf(v, 0.0f);
                    outp[m * 256 + co] = v;           // D col = l&15 -> co
                }
            }
        }
    }
}

// ---------------------------------------------------------------------------
// Kernel 5: final conv 256->42 (padded 48).  Same MFMA structure; 4 waves
// split K by tap groups {3,2,2,2}; partials reduced through LDS (X reused).
// Output (K,42,7,7).  Same read-swizzle fix as conv_mfma_kernel.
// ---------------------------------------------------------------------------
__global__ __launch_bounds__(256, 2) void conv5_mfma_kernel(
        const float* __restrict__ in, float* __restrict__ out,
        const ushort_t* __restrict__ wh, const ushort_t* __restrict__ wl,
        const float* __restrict__ b5) {
    __shared__ ushort_t X[2][64 * 256];
    const int roi = blockIdx.x, t = threadIdx.x;
    stage_roi(in + (size_t)roi * 49 * CC, X[0], X[1], t);
    __syncthreads();

    const int wv = t >> 6, l = t & 63;
    const int lr = l & 15, lk = l >> 4;
    const int lk16 = lk * 16;

    f32x4 acc[4][3];
    #pragma unroll
    for (int a = 0; a < 4; ++a)
        #pragma unroll
        for (int b = 0; b < 3; ++b) acc[a][b] = {0.f, 0.f, 0.f, 0.f};

    const int bvoff = (lr * 256 + lk * 8) * 2;
    const char* Xhc = (const char*)X[0];
    const char* Xlc = (const char*)X[1];
    const int t0 = (wv == 0) ? 0 : (2 * wv + 1);
    const int t1 = 2 * wv + 3;

    for (int tap = t0; tap < t1; ++tap) {
        const int ky = tap / 3 - 1, kx = tap % 3 - 1;
        int arow[4], amask[4];
        #pragma unroll
        for (int mt = 0; mt < 4; ++mt) {
            int m = mt * 16 + lr;
            int py = m / 7, px = m - py * 7;
            int y = py + ky, x = px + kx;
            bool ok = (m < 49) && (y >= 0) && (y < 7) && (x >= 0) && (x < 7);
            int srow = ok ? (y * 7 + x) : 63;
            arow[mt]  = srow * 512;
            amask[mt] = (srow & 7) << 4;
        }
        const char* wht = (const char*)wh + tap * 24576;   // 48*256*2
        const char* wlt = (const char*)wl + tap * 24576;
        #pragma unroll
        for (int kc = 0; kc < 8; ++kc) {
            short8 ah[4], al[4];
            #pragma unroll
            for (int mt = 0; mt < 4; ++mt) {
                const int off = arow[mt] + ((lk16 + kc * 64) ^ amask[mt]);
                ah[mt] = *(const short8*)(Xhc + off);
                al[mt] = *(const short8*)(Xlc + off);
            }
            #pragma unroll
            for (int nt = 0; nt < 3; ++nt) {
                const int woff = bvoff + nt * 8192 + kc * 64;
                short8 bh = *(const short8*)(wht + woff);
                short8 bl = *(const short8*)(wlt + woff);
                #pragma unroll
                for (int mt = 0; mt < 4; ++mt)
                    acc[mt][nt] = __builtin_amdgcn_mfma_f32_16x16x32_bf16(ah[mt], bh, acc[mt][nt], 0, 0, 0);
                #pragma unroll
                for (int mt = 0; mt < 4; ++mt)
                    acc[mt][nt] = __builtin_amdgcn_mfma_f32_16x16x32_bf16(al[mt], bh, acc[mt][nt], 0, 0, 0);
                #pragma unroll
                for (int mt = 0; mt < 4; ++mt)
                    acc[mt][nt] = __builtin_amdgcn_mfma_f32_16x16x32_bf16(ah[mt], bl, acc[mt][nt], 0, 0, 0);
            }
        }
    }

    __syncthreads();                       // all waves done reading X
    float* P = (float*)X;                  // reuse: [wave][m64][n48] = 48KB
    #pragma unroll
    for (int nt = 0; nt < 3; ++nt)
        #pragma unroll
        for (int mt = 0; mt < 4; ++mt)
            #pragma unroll
            for (int r = 0; r < 4; ++r) {
                int m = mt * 16 + lk * 4 + r;
                P[wv * 3072 + m * 48 + nt * 16 + lr] = acc[mt][nt][r];
            }
    __syncthreads();

    for (int i = t; i < 49 * CO5; i += 256) {     // 2058 outputs
        int n = i / 49, m = i % 49;
        float s = P[m * 48 + n] + P[3072 + m * 48 + n]
                + P[6144 + m * 48 + n] + P[9216 + m * 48 + n] + b5[n];
        out[(size_t)roi * (49 * CO5) + i] = s;    // out[roi][co][py][px]
    }
}

// ---------------------------------------------------------------------------
extern "C" void kernel_launch(void* const* d_in, const int* in_sizes, int n_in,
                              void* d_out, int out_size, void* d_ws, size_t ws_size,
                              hipStream_t stream) {
    const float* features = (const float*)d_in[0];
    const float* rois     = (const float*)d_in[1];
    const float* W1 = (const float*)d_in[2];
    const float* b1 = (const float*)d_in[3];
    const float* W2 = (const float*)d_in[4];
    const float* b2 = (const float*)d_in[5];
    const float* W3 = (const float*)d_in[6];
    const float* b3 = (const float*)d_in[7];
    const float* W4 = (const float*)d_in[8];
    const float* b4 = (const float*)d_in[9];
    const float* W5 = (const float*)d_in[10];
    const float* b5 = (const float*)d_in[11];
    float* out = (float*)d_out;

    const int K = in_sizes[1] / 5;   // 1024 rois

    // workspace layout (bytes)
    char* wsb = (char*)d_ws;
    float* ft   = (float*)wsb;                                // 31,129,600 B
    float* buf0 = (float*)(wsb + 31129600);                   // 51,380,224 B
    char* wb = wsb + 31129600 + 51380224;
    ushort_t* w1h = (ushort_t*)(wb + 0 * 1179648);
    ushort_t* w1l = (ushort_t*)(wb + 1 * 1179648);
    ushort_t* w2h = (ushort_t*)(wb + 2 * 1179648);
    ushort_t* w2l = (ushort_t*)(wb + 3 * 1179648);
    ushort_t* w3h = (ushort_t*)(wb + 4 * 1179648);
    ushort_t* w3l = (ushort_t*)(wb + 5 * 1179648);
    ushort_t* w4h = (ushort_t*)(wb + 6 * 1179648);
    ushort_t* w4l = (ushort_t*)(wb + 7 * 1179648);
    ushort_t* w5h = (ushort_t*)(wb + 8 * 1179648);
    ushort_t* w5l = (ushort_t*)(wb + 8 * 1179648 + 221184);
    // total = 92,389,376 B

    // 1. feature transpose
    {
        dim3 grid((WW + 31) / 32, CC / 32, BB * HH);
        dim3 block(32, 8);
        ftrans_kernel<<<grid, block, 0, stream>>>(features, ft);
    }
    // 2. weight prep (hi/lo bf16, [tap][co][ci])
    wprep_kernel<<<2304, 256, 0, stream>>>(W1, w1h, w1l);
    wprep_kernel<<<2304, 256, 0, stream>>>(W2, w2h, w2l);
    wprep_kernel<<<2304, 256, 0, stream>>>(W3, w3h, w3l);
    wprep_kernel<<<2304, 256, 0, stream>>>(W4, w4h, w4l);
    wprep5_kernel<<<432, 256, 0, stream>>>(W5, w5h, w5l);
    // 3. roi align -> buf0
    roialign_kernel<<<K, 256, 0, stream>>>(ft, rois, buf0);
    // 4. conv chain on MFMA, in-place on buf0
    conv_mfma_kernel<<<K, 256, 0, stream>>>(buf0, buf0, w1h, w1l, b1, 1);
    conv_mfma_kernel<<<K, 256, 0, stream>>>(buf0, buf0, w2h, w2l, b2, 1);
    conv_mfma_kernel<<<K, 256, 0, stream>>>(buf0, buf0, w3h, w3l, b3, 1);
    conv_mfma_kernel<<<K, 256, 0, stream>>>(buf0, buf0, w4h, w4l, b4, 1);
    // 5. final conv -> out
    conv5_mfma_kernel<<<K, 256, 0, stream>>>(buf0, out, w5h, w5l, b5);
}